// Round 4
// baseline (1184.212 us; speedup 1.0000x reference)
//
#include <hip/hip_runtime.h>

#define BB 4
#define TT 1024
#define CCH 2048
#define HH 16
#define HDIM 128
#define NBLK 1024
#define MM (BB*TT)          // 4096
#define N1 (3*CCH)          // 6144
#define NQT 16              // T / 64

typedef _Float16 f16;
typedef _Float16 half8 __attribute__((ext_vector_type(8)));
typedef _Float16 half4 __attribute__((ext_vector_type(4)));
typedef float floatx4 __attribute__((ext_vector_type(4)));

// async global->LDS, 16B per lane. LDS dest = wave-uniform base + lane*16.
__device__ __forceinline__ void g2lds16(const void* g, void* l) {
    __builtin_amdgcn_global_load_lds((const __attribute__((address_space(1))) void*)g,
                                     (__attribute__((address_space(3))) void*)l, 16, 0, 0);
}

// ---- fused prep: z=0 transpose Wa -> WaT f16, z=1 Wp -> WpT, z=2 cvt x -> f16 ----
__global__ void k_prep(const float* __restrict__ Wa, const float* __restrict__ Wp,
                       const float* __restrict__ x,
                       f16* __restrict__ WaT, f16* __restrict__ WpT,
                       f16* __restrict__ x16) {
    int z = blockIdx.z;
    if (z == 2) {   // convert: grid-stride over MM*CCH/4 float4s
        int i = (blockIdx.y * 192 + blockIdx.x) * 256 + threadIdx.x + threadIdx.y * 32;
        if (i >= MM * CCH / 4) return;
        float4 v = ((const float4*)x)[i];
        union { ushort4 u; f16 h[4]; } o;
        o.h[0] = (f16)v.x; o.h[1] = (f16)v.y; o.h[2] = (f16)v.z; o.h[3] = (f16)v.w;
        ((ushort4*)x16)[i] = o.u;
        return;
    }
    const float* in = (z == 0) ? Wa : Wp;
    f16* out = (z == 0) ? WaT : WpT;
    int Cc = (z == 0) ? N1 : CCH;
    if (blockIdx.x * 32 >= Cc) return;
    __shared__ float tile[32][33];
    int c0 = blockIdx.x * 32, r0 = blockIdx.y * 32;
    int tx = threadIdx.x, ty = threadIdx.y;
#pragma unroll
    for (int k = 0; k < 4; k++) {
        int r = ty + k * 8;
        tile[r][tx] = in[(size_t)(r0 + r) * Cc + c0 + tx];
    }
    __syncthreads();
#pragma unroll
    for (int k = 0; k < 4; k++) {
        int r = ty + k * 8;
        out[(size_t)(c0 + r) * CCH + r0 + tx] = (f16)tile[tx][r];
    }
}

// ------- transpose f16 per-head [T][HD] -> [HD][T] (for V) -------
__global__ void k_trv(const f16* __restrict__ in, f16* __restrict__ out) {
    __shared__ f16 tile[32][34];
    int bh = blockIdx.z;
    int h0 = blockIdx.x * 32, t0 = blockIdx.y * 32;
    int tx = threadIdx.x, ty = threadIdx.y;
#pragma unroll
    for (int k = 0; k < 4; k++) {
        int t = ty + k * 8;
        tile[t][tx] = in[((size_t)bh * TT + t0 + t) * HDIM + h0 + tx];
    }
    __syncthreads();
#pragma unroll
    for (int k = 0; k < 4; k++) {
        int r = ty + k * 8;
        out[((size_t)bh * HDIM + h0 + r) * TT + t0 + tx] = tile[tx][r];
    }
}

// ---------------- global histogram over all B*T tokens ----------------
__global__ void k_hist(const int* __restrict__ tok, int* __restrict__ cnt) {
    int i = blockIdx.x * blockDim.x + threadIdx.x;
    if (i < MM) atomicAdd(cnt + tok[i], 1);
}

// ------- per-batch inclusive scan of 1/count; also padding bias -------
__global__ __launch_bounds__(1024) void k_scan(const int* __restrict__ tok,
                                               const int* __restrict__ cnt,
                                               const int* __restrict__ pm,
                                               float* __restrict__ tpos,
                                               float* __restrict__ pb) {
    __shared__ float s[TT];
    int b = blockIdx.x, t = threadIdx.x;
    s[t] = 1.0f / ((float)cnt[tok[b * TT + t]] + 1e-10f);
    __syncthreads();
    for (int off = 1; off < TT; off <<= 1) {
        float add = (t >= off) ? s[t - off] : 0.0f;
        __syncthreads();
        s[t] += add;
        __syncthreads();
    }
    tpos[b * TT + t] = s[t];
    pb[b * TT + t] = pm[b * TT + t] ? 0.0f : -1e30f;
}

// ------- GEMM: A[M][K] f16, Bt[N][K] f16; 128x128 tile, BK=32 --------
// 4 waves, 64x64 wave tile (4x4 of 16x16x32 MFMA). Staging pointers hoisted
// and advanced by +=32/iter (kills the v_lshl_add_u64 chains of r2/r3).
// MODE 0: fp32 C write (GEMM2). MODE 1: fused rope/override/v-scale epilogue;
// the rotate-half pair (hd j, j+64) spans waves -> one-time C-tile exchange
// through a 32KB LDS buffer unioned with As/Bs.
template <int MODE>
__global__ __launch_bounds__(256) void k_gemm(const f16* __restrict__ A,
                                              const f16* __restrict__ Bt,
                                              void* __restrict__ Cp,
                                              const float* __restrict__ tpos,
                                              const float* __restrict__ cs,
                                              f16* __restrict__ qr,
                                              f16* __restrict__ kr,
                                              f16* __restrict__ vsc,
                                              int Mdim, int Ndim, int Kdim) {
    const float SCALE = 0.08838834764831845f;  // 1/sqrt(128), folded into q
    __shared__ __align__(16) f16 smem[128 * 128];   // 32 KB; loop uses first 16 KB
    f16* As = smem;               // [128][32]
    f16* Bs = smem + 128 * 32;    // [128][32]
    int nbn = Ndim >> 7;
    int bm = blockIdx.x / nbn, bn = blockIdx.x % nbn;
    int tid = threadIdx.x;
    int w = tid >> 6, lane = tid & 63, quad = lane >> 4, l16 = lane & 15;
    int wm = (w & 1) << 6, wn = (w >> 1) << 6;
    int rsub = lane >> 2;            // 0..15
    int csub = (lane & 3) << 3;      // 0,8,16,24
    // hoisted staging pointers (advance += 32 per k-iter)
    const f16* pa0 = A  + (size_t)((bm << 7) + w * 32 + rsub) * Kdim + csub;
    const f16* pa1 = pa0 + (size_t)16 * Kdim;
    const f16* pb0 = Bt + (size_t)((bn << 7) + w * 32 + rsub) * Kdim + csub;
    const f16* pb1 = pb0 + (size_t)16 * Kdim;
    f16* lda0 = &As[(w * 32) * 32];
    f16* lda1 = &As[(w * 32 + 16) * 32];
    f16* ldb0 = &Bs[(w * 32) * 32];
    f16* ldb1 = &Bs[(w * 32 + 16) * 32];
    floatx4 acc[4][4];
#pragma unroll
    for (int i = 0; i < 4; i++)
#pragma unroll
        for (int j = 0; j < 4; j++) acc[i][j] = (floatx4){0.f, 0.f, 0.f, 0.f};
    int nk = Kdim >> 5;
    for (int kt = 0; kt < nk; kt++) {
        __syncthreads();
        g2lds16(pa0, lda0); g2lds16(pa1, lda1);
        g2lds16(pb0, ldb0); g2lds16(pb1, ldb1);
        pa0 += 32; pa1 += 32; pb0 += 32; pb1 += 32;
        __syncthreads();
        half8 af[4], bfr[4];
#pragma unroll
        for (int i = 0; i < 4; i++) af[i] = *(const half8*)&As[(wm + i * 16 + l16) * 32 + (quad << 3)];
#pragma unroll
        for (int j = 0; j < 4; j++) bfr[j] = *(const half8*)&Bs[(wn + j * 16 + l16) * 32 + (quad << 3)];
#pragma unroll
        for (int i = 0; i < 4; i++)
#pragma unroll
            for (int j = 0; j < 4; j++)
                acc[i][j] = __builtin_amdgcn_mfma_f32_16x16x32_f16(af[i], bfr[j], acc[i][j], 0, 0, 0);
    }
    // C position: row = bm*128 + wm + i*16 + quad*4 + r ; col = wn + j*16 + l16
    int rl0 = wm + (quad << 2);           // local row base
    int cl0 = wn + l16;                   // local col base
    if (MODE == 0) {
        int rb = (bm << 7) + rl0;
        int cb = (bn << 7) + cl0;
#pragma unroll
        for (int i = 0; i < 4; i++)
#pragma unroll
            for (int j = 0; j < 4; j++)
#pragma unroll
                for (int r = 0; r < 4; r++)
                    ((float*)Cp)[(size_t)(rb + i * 16 + r) * Ndim + cb + j * 16] = acc[i][j][r];
    } else {
        int type = bn >> 4;          // 0=q, 1=k, 2=v (16 col-tiles per 2048-chunk)
        int h = bn & 15;
        if (type == 2) {
#pragma unroll
            for (int i = 0; i < 4; i++)
#pragma unroll
                for (int r = 0; r < 4; r++) {
                    int row = (bm << 7) + rl0 + i * 16 + r;
                    float ve = expf(cs[row]);
                    size_t ob = ((size_t)((row >> 10) * HH + h) * TT + (row & 1023)) * HDIM + cl0;
#pragma unroll
                    for (int j = 0; j < 4; j++)
                        vsc[ob + j * 16] = (f16)(acc[i][j][r] * ve);
                }
        } else {
            // phase 1: park C tile in LDS (f16) for cross-wave rotate-half pairing
            __syncthreads();
#pragma unroll
            for (int i = 0; i < 4; i++)
#pragma unroll
                for (int j = 0; j < 4; j++)
#pragma unroll
                    for (int r = 0; r < 4; r++)
                        smem[(rl0 + i * 16 + r) * 128 + cl0 + j * 16] = (f16)acc[i][j][r];
            __syncthreads();
            f16* outp = (type == 0) ? qr : kr;
            float invf[4];
#pragma unroll
            for (int j = 0; j < 4; j++)
                invf[j] = expf((float)(((cl0 + j * 16) & 63)) * -0.14391156929f);  // 10000^(-j/64)
#pragma unroll
            for (int i = 0; i < 4; i++)
#pragma unroll
                for (int r = 0; r < 4; r++) {
                    int rloc = rl0 + i * 16 + r;
                    int row = (bm << 7) + rloc;            // global bt
                    float tp = tpos[row], csv = cs[row];
                    size_t ob = ((size_t)((row >> 10) * HH + h) * TT + (row & 1023)) * HDIM + cl0;
#pragma unroll
                    for (int j = 0; j < 4; j++) {
                        int col = cl0 + j * 16;
                        float own = acc[i][j][r];
                        float par = (float)smem[rloc * 128 + (col ^ 64)];
                        float sn, cn;
                        sincosf(tp * invf[j], &sn, &cn);
                        float o = (col < 64) ? (own * cn - par * sn)
                                             : (own * cn + par * sn);
                        if (type == 0) {
                            if (col == 127) o = 1.0f;      // q[...,-1]=1
                            o *= SCALE;
                        } else {
                            if (col == 127) o = csv;       // k[...,-1]=cum_scores
                        }
                        outp[ob + j * 16] = (f16)o;
                    }
                }
        }
    }
}

// ---------------- causal flash attention, S^T formulation ----------------
// Block handles TWO q-tiles (p, NQT-1-p) sequentially -> every block does
// exactly NQT+1 kv-iters (triangular load balance). 4 waves, wave w owns
// q columns w*16+l16 within the 64-q tile.
__global__ __launch_bounds__(256) void k_attn(const f16* __restrict__ qr,
                                              const f16* __restrict__ kr,
                                              const f16* __restrict__ vt,
                                              const float* __restrict__ pb,
                                              f16* __restrict__ y) {
    __shared__ __align__(16) f16 Ks[64 * 136];   // [kv][hd], pad 128->136
    __shared__ __align__(16) f16 Vs[128 * 72];   // [hd][kv], pad 64->72
    __shared__ float pbs[64];
    int p = blockIdx.x & (NQT / 2 - 1);
    int bh = blockIdx.x >> 3;
    int b = bh >> 4, h = bh & 15;
    int tid = threadIdx.x;
    int w = tid >> 6, lane = tid & 63, quad = lane >> 4, l16 = lane & 15;
#pragma unroll
    for (int pass = 0; pass < 2; pass++) {
        int qt = pass ? (NQT - 1 - p) : p;
        int q0 = qt << 6;
        int qg = q0 + w * 16 + l16;                  // this lane's q column
        const f16* Qp = qr + ((size_t)bh * TT + qg) * HDIM;
        half8 qf[4];                                  // B-op: Q[q=l16][hd=kc*32+quad*8+e]
#pragma unroll
        for (int kc = 0; kc < 4; kc++) qf[kc] = *(const half8*)&Qp[kc * 32 + (quad << 3)];
        floatx4 O[8];                                 // O^T[hd][q] C-frags
#pragma unroll
        for (int i = 0; i < 8; i++) O[i] = (floatx4){0.f, 0.f, 0.f, 0.f};
        float mx = -1e30f, ls = 0.f;
        for (int kt = 0; kt <= qt; kt++) {
            __syncthreads();
            const f16* Kb = kr + ((size_t)bh * TT + (kt << 6)) * HDIM;
            const f16* Vb = vt + (size_t)bh * HDIM * TT + (kt << 6);
#pragma unroll
            for (int i = 0; i < 4; i++) {
                int seg = tid + (i << 8);
                int krow = seg >> 4, kcol = (seg & 15) << 3;
                *(uint4*)&Ks[krow * 136 + kcol] = *(const uint4*)&Kb[(size_t)krow * HDIM + kcol];
                int vrow = seg >> 3, vcol = (seg & 7) << 3;
                *(uint4*)&Vs[vrow * 72 + vcol] = *(const uint4*)&Vb[(size_t)vrow * TT + vcol];
            }
            if (tid < 64) pbs[tid] = pb[b * TT + (kt << 6) + tid];
            __syncthreads();
            // S^T = K * Q^T : C-layout S^T[kv=quad*4+i][q=l16]
            floatx4 Sv[4];
#pragma unroll
            for (int mc = 0; mc < 4; mc++) Sv[mc] = (floatx4){0.f, 0.f, 0.f, 0.f};
#pragma unroll
            for (int kc = 0; kc < 4; kc++)
#pragma unroll
                for (int mc = 0; mc < 4; mc++) {
                    half8 kf = *(const half8*)&Ks[(mc * 16 + l16) * 136 + kc * 32 + (quad << 3)];
                    Sv[mc] = __builtin_amdgcn_mfma_f32_16x16x32_f16(kf, qf[kc], Sv[mc], 0, 0, 0);
                }
            // mask + bias + online softmax (per q column = per lane)
            float pv[4][4];
            float mnew = mx;
#pragma unroll
            for (int mc = 0; mc < 4; mc++) {
                float4 pbv = *(const float4*)&pbs[mc * 16 + (quad << 2)];
#pragma unroll
                for (int i = 0; i < 4; i++) {
                    int kv = (kt << 6) + mc * 16 + (quad << 2) + i;
                    float s = (kv <= qg) ? Sv[mc][i] + ((const float*)&pbv)[i] : -1e30f;
                    pv[mc][i] = s;
                    mnew = fmaxf(mnew, s);
                }
            }
            mnew = fmaxf(mnew, __shfl_xor(mnew, 16));
            mnew = fmaxf(mnew, __shfl_xor(mnew, 32));
            float al = __expf(mx - mnew);
            mx = mnew;
            float psum = 0.f;
#pragma unroll
            for (int mc = 0; mc < 4; mc++)
#pragma unroll
                for (int i = 0; i < 4; i++) {
                    float e = __expf(pv[mc][i] - mnew);
                    pv[mc][i] = e;
                    psum += e;
                }
            psum += __shfl_xor(psum, 16);
            psum += __shfl_xor(psum, 32);
            ls = ls * al + psum;
#pragma unroll
            for (int hm = 0; hm < 8; hm++)
#pragma unroll
                for (int i = 0; i < 4; i++) O[hm][i] *= al;
            // P^T as B-operand of 16x16x16 (k=quad*4+i == C rows). A = V^T.
            half4 pf[4];
#pragma unroll
            for (int mc = 0; mc < 4; mc++) {
                pf[mc][0] = (f16)pv[mc][0]; pf[mc][1] = (f16)pv[mc][1];
                pf[mc][2] = (f16)pv[mc][2]; pf[mc][3] = (f16)pv[mc][3];
            }
#pragma unroll
            for (int mc = 0; mc < 4; mc++)
#pragma unroll
                for (int hm = 0; hm < 8; hm++) {
                    half4 vf = *(const half4*)&Vs[(hm * 16 + l16) * 72 + mc * 16 + (quad << 2)];
                    O[hm] = __builtin_amdgcn_mfma_f32_16x16x16f16(vf, pf[mc], O[hm], 0, 0, 0);
                }
        }
        float inv = 1.0f / ls;
#pragma unroll
        for (int hm = 0; hm < 8; hm++) {
            half4 ov;
#pragma unroll
            for (int i = 0; i < 4; i++) ov[i] = (f16)(O[hm][i] * inv);
            *(half4*)&y[((size_t)b * TT + qg) * CCH + h * HDIM + hm * 16 + (quad << 2)] = ov;
        }
        __syncthreads();   // protect LDS before next pass restages
    }
}

extern "C" void kernel_launch(void* const* d_in, const int* in_sizes, int n_in,
                              void* d_out, int out_size, void* d_ws, size_t ws_size,
                              hipStream_t stream) {
    const float* x   = (const float*)d_in[0];
    const float* cs  = (const float*)d_in[1];
    const int*   tok = (const int*)d_in[2];
    const int*   pm  = (const int*)d_in[3];
    const float* Wa  = (const float*)d_in[4];
    const float* Wp  = (const float*)d_in[5];
    float* out = (float*)d_out;
    char* ws = (char*)d_ws;

    f16* x16 = (f16*)(ws + 0);             // 16 MB ; reused as y after GEMM1
    f16* WaT = (f16*)(ws + 16777216);      // 24 MB
    f16* vt  = (f16*)(ws + 41943040);      // 16 MB   [bh][hd][t]
    f16* WpT = (f16*)(ws + 58720256);      //  8 MB
    f16* qr  = (f16*)(ws + 92274688);      // 16 MB
    f16* kr  = (f16*)(ws + 109051904);     // 16 MB
    f16* vsc = (f16*)(ws + 125829120);     // 16 MB
    int*   cnt  = (int*)(ws + 142606336);  // 4 KB
    float* tpos = (float*)(ws + 142610432);// 16 KB
    float* pb   = (float*)(ws + 142626816);// 16 KB
    f16* y   = x16;

    hipMemsetAsync(cnt, 0, NBLK * sizeof(int), stream);
    k_hist<<<MM / 256, 256, 0, stream>>>(tok, cnt);
    k_scan<<<BB, TT, 0, stream>>>(tok, cnt, pm, tpos, pb);
    k_prep<<<dim3(N1 / 32, CCH / 32, 3), dim3(32, 8), 0, stream>>>(Wa, Wp, x, WaT, WpT, x16);
    k_gemm<1><<<(MM / 128) * (N1 / 128), 256, 0, stream>>>(x16, WaT, nullptr, tpos, cs,
                                                           qr, kr, vsc, MM, N1, CCH);
    k_trv<<<dim3(4, 32, BB * HH), dim3(32, 8), 0, stream>>>(vsc, vt);
    k_attn<<<BB * HH * (NQT / 2), 256, 0, stream>>>(qr, kr, vt, pb, y);
    k_gemm<0><<<(MM / 128) * (CCH / 128), 256, 0, stream>>>(y, WpT, out, nullptr, nullptr,
                                                            nullptr, nullptr, nullptr, MM, CCH, CCH);
}

// Round 5
// 428.988 us; speedup vs baseline: 2.7605x; 2.7605x over previous
//
#include <hip/hip_runtime.h>

#define BB 4
#define TT 1024
#define CCH 2048
#define HH 16
#define HDIM 128
#define NBLK 1024
#define MM (BB*TT)          // 4096
#define N1 (3*CCH)          // 6144
#define NQT 16              // T / 64

typedef _Float16 f16;
typedef _Float16 half8 __attribute__((ext_vector_type(8)));
typedef _Float16 half4 __attribute__((ext_vector_type(4)));
typedef float floatx4 __attribute__((ext_vector_type(4)));

// async global->LDS, 16B per lane. LDS dest = wave-uniform base + lane*16.
__device__ __forceinline__ void g2lds16(const void* g, void* l) {
    __builtin_amdgcn_global_load_lds((const __attribute__((address_space(1))) void*)g,
                                     (__attribute__((address_space(3))) void*)l, 16, 0, 0);
}

// ---- fused prep: z=0 transpose Wa -> WaT f16, z=1 Wp -> WpT, z=2 cvt x -> f16 ----
__global__ void k_prep(const float* __restrict__ Wa, const float* __restrict__ Wp,
                       const float* __restrict__ x,
                       f16* __restrict__ WaT, f16* __restrict__ WpT,
                       f16* __restrict__ x16) {
    int z = blockIdx.z;
    if (z == 2) {   // convert: MM*CCH/4 float4s
        int i = (blockIdx.y * 192 + blockIdx.x) * 256 + threadIdx.x + threadIdx.y * 32;
        if (i >= MM * CCH / 4) return;
        float4 v = ((const float4*)x)[i];
        union { ushort4 u; f16 h[4]; } o;
        o.h[0] = (f16)v.x; o.h[1] = (f16)v.y; o.h[2] = (f16)v.z; o.h[3] = (f16)v.w;
        ((ushort4*)x16)[i] = o.u;
        return;
    }
    const float* in = (z == 0) ? Wa : Wp;
    f16* out = (z == 0) ? WaT : WpT;
    int Cc = (z == 0) ? N1 : CCH;
    if (blockIdx.x * 32 >= Cc) return;
    __shared__ float tile[32][33];
    int c0 = blockIdx.x * 32, r0 = blockIdx.y * 32;
    int tx = threadIdx.x, ty = threadIdx.y;
#pragma unroll
    for (int k = 0; k < 4; k++) {
        int r = ty + k * 8;
        tile[r][tx] = in[(size_t)(r0 + r) * Cc + c0 + tx];
    }
    __syncthreads();
#pragma unroll
    for (int k = 0; k < 4; k++) {
        int r = ty + k * 8;
        out[(size_t)(c0 + r) * CCH + r0 + tx] = (f16)tile[tx][r];
    }
}

// ------- transpose f16 per-head [T][HD] -> [HD][T] (for V) -------
__global__ void k_trv(const f16* __restrict__ in, f16* __restrict__ out) {
    __shared__ f16 tile[32][34];
    int bh = blockIdx.z;
    int h0 = blockIdx.x * 32, t0 = blockIdx.y * 32;
    int tx = threadIdx.x, ty = threadIdx.y;
#pragma unroll
    for (int k = 0; k < 4; k++) {
        int t = ty + k * 8;
        tile[t][tx] = in[((size_t)bh * TT + t0 + t) * HDIM + h0 + tx];
    }
    __syncthreads();
#pragma unroll
    for (int k = 0; k < 4; k++) {
        int r = ty + k * 8;
        out[((size_t)bh * HDIM + h0 + r) * TT + t0 + tx] = tile[tx][r];
    }
}

// ---------------- global histogram over all B*T tokens ----------------
__global__ void k_hist(const int* __restrict__ tok, int* __restrict__ cnt) {
    int i = blockIdx.x * blockDim.x + threadIdx.x;
    if (i < MM) atomicAdd(cnt + tok[i], 1);
}

// ------- per-batch inclusive scan of 1/count; also padding bias -------
__global__ __launch_bounds__(1024) void k_scan(const int* __restrict__ tok,
                                               const int* __restrict__ cnt,
                                               const int* __restrict__ pm,
                                               float* __restrict__ tpos,
                                               float* __restrict__ pb) {
    __shared__ float s[TT];
    int b = blockIdx.x, t = threadIdx.x;
    s[t] = 1.0f / ((float)cnt[tok[b * TT + t]] + 1e-10f);
    __syncthreads();
    for (int off = 1; off < TT; off <<= 1) {
        float add = (t >= off) ? s[t - off] : 0.0f;
        __syncthreads();
        s[t] += add;
        __syncthreads();
    }
    tpos[b * TT + t] = s[t];
    pb[b * TT + t] = pm[b * TT + t] ? 0.0f : -1e30f;
}

// ------- GEMM: A[M][K] f16, Bt[N][K] f16; 128x128 tile, BK=32 --------
// EXACT round-3 structure (known good: 150us, 94MB fetch, 50MB write).
// Wave tile = 32 rows x 128 cols so the rotate-half pair (hd j, j+64) lives in
// the SAME lane, same reg index (acc[i][jc] vs acc[i][jc+4]) -> in-register RoPE.
// MODE 0: plain fp32 C write (GEMM2). MODE 1: fused rope/override/v-scale epilogue.
// NOTE r4 post-mortem: restructuring this (LDS union + hoisted pointers +
// 64x64 wave tile) triggered per-iteration scratch traffic (WRITE_SIZE 5.6GB).
// Do not touch without watching WRITE_SIZE.
template <int MODE>
__global__ __launch_bounds__(256) void k_gemm(const f16* __restrict__ A,
                                              const f16* __restrict__ Bt,
                                              void* __restrict__ Cp,
                                              const float* __restrict__ tpos,
                                              const float* __restrict__ cs,
                                              f16* __restrict__ qr,
                                              f16* __restrict__ kr,
                                              f16* __restrict__ vsc,
                                              int Mdim, int Ndim, int Kdim) {
    const float SCALE = 0.08838834764831845f;  // 1/sqrt(128), folded into q
    __shared__ __align__(16) f16 As[128 * 32];
    __shared__ __align__(16) f16 Bs[128 * 32];
    int nbn = Ndim >> 7;
    int bm = blockIdx.x / nbn, bn = blockIdx.x % nbn;
    int tid = threadIdx.x;
    int w = tid >> 6, lane = tid & 63, quad = lane >> 4, l16 = lane & 15;
    const f16* Ab = A + (size_t)(bm << 7) * Kdim;
    const f16* Bb = Bt + (size_t)(bn << 7) * Kdim;
    int rsub = lane >> 2;            // 0..15
    int csub = (lane & 3) << 3;      // 0,8,16,24
    floatx4 acc[2][8];
#pragma unroll
    for (int i = 0; i < 2; i++)
#pragma unroll
        for (int j = 0; j < 8; j++) acc[i][j] = (floatx4){0.f, 0.f, 0.f, 0.f};
    int nk = Kdim >> 5;
    for (int kt = 0; kt < nk; kt++) {
        __syncthreads();
#pragma unroll
        for (int i = 0; i < 2; i++) {
            int row = w * 32 + i * 16 + rsub;
            g2lds16(Ab + (size_t)row * Kdim + (kt << 5) + csub, &As[(w * 32 + i * 16) * 32]);
            g2lds16(Bb + (size_t)row * Kdim + (kt << 5) + csub, &Bs[(w * 32 + i * 16) * 32]);
        }
        __syncthreads();
        half8 af[2], bfr[8];
#pragma unroll
        for (int i = 0; i < 2; i++) af[i] = *(const half8*)&As[(w * 32 + i * 16 + l16) * 32 + (quad << 3)];
#pragma unroll
        for (int j = 0; j < 8; j++) bfr[j] = *(const half8*)&Bs[(j * 16 + l16) * 32 + (quad << 3)];
#pragma unroll
        for (int i = 0; i < 2; i++)
#pragma unroll
            for (int j = 0; j < 8; j++)
                acc[i][j] = __builtin_amdgcn_mfma_f32_16x16x32_f16(af[i], bfr[j], acc[i][j], 0, 0, 0);
    }
    // C rows for this thread: bm*128 + w*32 + i*16 + quad*4 + r ; cols j*16 + l16
    int row0 = (bm << 7) + w * 32 + (quad << 2);
    if (MODE == 0) {
        int cb = (bn << 7) + l16;
#pragma unroll
        for (int i = 0; i < 2; i++)
#pragma unroll
            for (int j = 0; j < 8; j++)
#pragma unroll
                for (int r = 0; r < 4; r++)
                    ((float*)Cp)[(size_t)(row0 + i * 16 + r) * Ndim + cb + j * 16] = acc[i][j][r];
    } else {
        int type = bn >> 4;          // 0=q, 1=k, 2=v (16 col-tiles per 2048-chunk)
        int h = bn & 15;
        if (type < 2) {
            f16* outp = (type == 0) ? qr : kr;
            float invf[4];
#pragma unroll
            for (int jc = 0; jc < 4; jc++)
                invf[jc] = expf((float)(jc * 16 + l16) * -0.14391156929f);  // 10000^(-j/64)
#pragma unroll
            for (int i = 0; i < 2; i++)
#pragma unroll
                for (int r = 0; r < 4; r++) {
                    int row = row0 + i * 16 + r;           // global bt
                    float tp = tpos[row], csv = cs[row];
                    size_t ob = ((size_t)((row >> 10) * HH + h) * TT + (row & 1023)) * HDIM + l16;
#pragma unroll
                    for (int jc = 0; jc < 4; jc++) {
                        float a1 = acc[i][jc][r], a2 = acc[i][jc + 4][r];
                        float sn, cn;
                        sincosf(tp * invf[jc], &sn, &cn);
                        float o1 = a1 * cn - a2 * sn, o2 = a2 * cn + a1 * sn;
                        if (type == 0) {
                            if (jc == 3 && l16 == 15) o2 = 1.0f;      // q[...,-1]=1
                            o1 *= SCALE; o2 *= SCALE;
                        } else {
                            if (jc == 3 && l16 == 15) o2 = csv;       // k[...,-1]=cum_scores
                        }
                        outp[ob + jc * 16]      = (f16)o1;
                        outp[ob + jc * 16 + 64] = (f16)o2;
                    }
                }
        } else {
#pragma unroll
            for (int i = 0; i < 2; i++)
#pragma unroll
                for (int r = 0; r < 4; r++) {
                    int row = row0 + i * 16 + r;
                    float ve = expf(cs[row]);
                    size_t ob = ((size_t)((row >> 10) * HH + h) * TT + (row & 1023)) * HDIM + l16;
#pragma unroll
                    for (int jc = 0; jc < 8; jc++)
                        vsc[ob + jc * 16] = (f16)(acc[i][jc][r] * ve);
                }
        }
    }
}

// ---------------- causal flash attention, S^T formulation ----------------
// Block handles TWO q-tiles (p, NQT-1-p) sequentially -> every block does
// exactly NQT+1 kv-iters (triangular load balance). 4 waves, wave w owns
// q columns w*16+l16 within the 64-q tile.
__global__ __launch_bounds__(256) void k_attn(const f16* __restrict__ qr,
                                              const f16* __restrict__ kr,
                                              const f16* __restrict__ vt,
                                              const float* __restrict__ pb,
                                              f16* __restrict__ y) {
    __shared__ __align__(16) f16 Ks[64 * 136];   // [kv][hd], pad 128->136
    __shared__ __align__(16) f16 Vs[128 * 72];   // [hd][kv], pad 64->72
    __shared__ float pbs[64];
    int p = blockIdx.x & (NQT / 2 - 1);
    int bh = blockIdx.x >> 3;
    int b = bh >> 4, h = bh & 15;
    int tid = threadIdx.x;
    int w = tid >> 6, lane = tid & 63, quad = lane >> 4, l16 = lane & 15;
#pragma unroll
    for (int pass = 0; pass < 2; pass++) {
        int qt = pass ? (NQT - 1 - p) : p;
        int q0 = qt << 6;
        int qg = q0 + w * 16 + l16;                  // this lane's q column
        const f16* Qp = qr + ((size_t)bh * TT + qg) * HDIM;
        half8 qf[4];                                  // B-op: Q[q=l16][hd=kc*32+quad*8+e]
#pragma unroll
        for (int kc = 0; kc < 4; kc++) qf[kc] = *(const half8*)&Qp[kc * 32 + (quad << 3)];
        floatx4 O[8];                                 // O^T[hd][q] C-frags
#pragma unroll
        for (int i = 0; i < 8; i++) O[i] = (floatx4){0.f, 0.f, 0.f, 0.f};
        float mx = -1e30f, ls = 0.f;
        for (int kt = 0; kt <= qt; kt++) {
            __syncthreads();
            const f16* Kb = kr + ((size_t)bh * TT + (kt << 6)) * HDIM;
            const f16* Vb = vt + (size_t)bh * HDIM * TT + (kt << 6);
#pragma unroll
            for (int i = 0; i < 4; i++) {
                int seg = tid + (i << 8);
                int krow = seg >> 4, kcol = (seg & 15) << 3;
                *(uint4*)&Ks[krow * 136 + kcol] = *(const uint4*)&Kb[(size_t)krow * HDIM + kcol];
                int vrow = seg >> 3, vcol = (seg & 7) << 3;
                *(uint4*)&Vs[vrow * 72 + vcol] = *(const uint4*)&Vb[(size_t)vrow * TT + vcol];
            }
            if (tid < 64) pbs[tid] = pb[b * TT + (kt << 6) + tid];
            __syncthreads();
            // S^T = K * Q^T : C-layout S^T[kv=quad*4+i][q=l16]
            floatx4 Sv[4];
#pragma unroll
            for (int mc = 0; mc < 4; mc++) Sv[mc] = (floatx4){0.f, 0.f, 0.f, 0.f};
#pragma unroll
            for (int kc = 0; kc < 4; kc++)
#pragma unroll
                for (int mc = 0; mc < 4; mc++) {
                    half8 kf = *(const half8*)&Ks[(mc * 16 + l16) * 136 + kc * 32 + (quad << 3)];
                    Sv[mc] = __builtin_amdgcn_mfma_f32_16x16x32_f16(kf, qf[kc], Sv[mc], 0, 0, 0);
                }
            // mask + bias + online softmax (per q column = per lane)
            float pv[4][4];
            float mnew = mx;
#pragma unroll
            for (int mc = 0; mc < 4; mc++) {
                float4 pbv = *(const float4*)&pbs[mc * 16 + (quad << 2)];
#pragma unroll
                for (int i = 0; i < 4; i++) {
                    int kv = (kt << 6) + mc * 16 + (quad << 2) + i;
                    float s = (kv <= qg) ? Sv[mc][i] + ((const float*)&pbv)[i] : -1e30f;
                    pv[mc][i] = s;
                    mnew = fmaxf(mnew, s);
                }
            }
            mnew = fmaxf(mnew, __shfl_xor(mnew, 16));
            mnew = fmaxf(mnew, __shfl_xor(mnew, 32));
            float al = __expf(mx - mnew);
            mx = mnew;
            float psum = 0.f;
#pragma unroll
            for (int mc = 0; mc < 4; mc++)
#pragma unroll
                for (int i = 0; i < 4; i++) {
                    float e = __expf(pv[mc][i] - mnew);
                    pv[mc][i] = e;
                    psum += e;
                }
            psum += __shfl_xor(psum, 16);
            psum += __shfl_xor(psum, 32);
            ls = ls * al + psum;
#pragma unroll
            for (int hm = 0; hm < 8; hm++)
#pragma unroll
                for (int i = 0; i < 4; i++) O[hm][i] *= al;
            // P^T as B-operand of 16x16x16 (k=quad*4+i == C rows). A = V^T.
            half4 pf[4];
#pragma unroll
            for (int mc = 0; mc < 4; mc++) {
                pf[mc][0] = (f16)pv[mc][0]; pf[mc][1] = (f16)pv[mc][1];
                pf[mc][2] = (f16)pv[mc][2]; pf[mc][3] = (f16)pv[mc][3];
            }
#pragma unroll
            for (int mc = 0; mc < 4; mc++)
#pragma unroll
                for (int hm = 0; hm < 8; hm++) {
                    half4 vf = *(const half4*)&Vs[(hm * 16 + l16) * 72 + mc * 16 + (quad << 2)];
                    O[hm] = __builtin_amdgcn_mfma_f32_16x16x16f16(vf, pf[mc], O[hm], 0, 0, 0);
                }
        }
        float inv = 1.0f / ls;
#pragma unroll
        for (int hm = 0; hm < 8; hm++) {
            half4 ov;
#pragma unroll
            for (int i = 0; i < 4; i++) ov[i] = (f16)(O[hm][i] * inv);
            *(half4*)&y[((size_t)b * TT + qg) * CCH + h * HDIM + hm * 16 + (quad << 2)] = ov;
        }
        __syncthreads();   // protect LDS before next pass restages
    }
}

extern "C" void kernel_launch(void* const* d_in, const int* in_sizes, int n_in,
                              void* d_out, int out_size, void* d_ws, size_t ws_size,
                              hipStream_t stream) {
    const float* x   = (const float*)d_in[0];
    const float* cs  = (const float*)d_in[1];
    const int*   tok = (const int*)d_in[2];
    const int*   pm  = (const int*)d_in[3];
    const float* Wa  = (const float*)d_in[4];
    const float* Wp  = (const float*)d_in[5];
    float* out = (float*)d_out;
    char* ws = (char*)d_ws;

    f16* x16 = (f16*)(ws + 0);             // 16 MB ; reused as y after GEMM1
    f16* WaT = (f16*)(ws + 16777216);      // 24 MB
    f16* vt  = (f16*)(ws + 41943040);      // 16 MB   [bh][hd][t]
    f16* WpT = (f16*)(ws + 58720256);      //  8 MB
    f16* qr  = (f16*)(ws + 92274688);      // 16 MB
    f16* kr  = (f16*)(ws + 109051904);     // 16 MB
    f16* vsc = (f16*)(ws + 125829120);     // 16 MB
    int*   cnt  = (int*)(ws + 142606336);  // 4 KB
    float* tpos = (float*)(ws + 142610432);// 16 KB
    float* pb   = (float*)(ws + 142626816);// 16 KB
    f16* y   = x16;

    hipMemsetAsync(cnt, 0, NBLK * sizeof(int), stream);
    k_hist<<<MM / 256, 256, 0, stream>>>(tok, cnt);
    k_scan<<<BB, TT, 0, stream>>>(tok, cnt, pm, tpos, pb);
    k_prep<<<dim3(N1 / 32, CCH / 32, 3), dim3(32, 8), 0, stream>>>(Wa, Wp, x, WaT, WpT, x16);
    k_gemm<1><<<(MM / 128) * (N1 / 128), 256, 0, stream>>>(x16, WaT, nullptr, tpos, cs,
                                                           qr, kr, vsc, MM, N1, CCH);
    k_trv<<<dim3(4, 32, BB * HH), dim3(32, 8), 0, stream>>>(vsc, vt);
    k_attn<<<BB * HH * (NQT / 2), 256, 0, stream>>>(qr, kr, vt, pb, y);
    k_gemm<0><<<(MM / 128) * (CCH / 128), 256, 0, stream>>>(y, WpT, out, nullptr, nullptr,
                                                            nullptr, nullptr, nullptr, MM, CCH, CCH);
}

// Round 6
// 414.675 us; speedup vs baseline: 2.8558x; 1.0345x over previous
//
#include <hip/hip_runtime.h>

#define BB 4
#define TT 1024
#define CCH 2048
#define HH 16
#define HDIM 128
#define NBLK 1024
#define MM (BB*TT)          // 4096
#define N1 (3*CCH)          // 6144
#define NQT 16              // T / 64

typedef _Float16 f16;
typedef _Float16 half8 __attribute__((ext_vector_type(8)));
typedef _Float16 half4 __attribute__((ext_vector_type(4)));
typedef float floatx4 __attribute__((ext_vector_type(4)));

// async global->LDS, 16B per lane. LDS dest = wave-uniform base + lane*16.
__device__ __forceinline__ void g2lds16(const void* g, void* l) {
    __builtin_amdgcn_global_load_lds((const __attribute__((address_space(1))) void*)g,
                                     (__attribute__((address_space(3))) void*)l, 16, 0, 0);
}

// ---- fused prep: z=0 transpose Wa -> WaT f16, z=1 Wp -> WpT, z=2 cvt x -> f16 ----
__global__ void k_prep(const float* __restrict__ Wa, const float* __restrict__ Wp,
                       const float* __restrict__ x,
                       f16* __restrict__ WaT, f16* __restrict__ WpT,
                       f16* __restrict__ x16) {
    int z = blockIdx.z;
    if (z == 2) {   // convert: MM*CCH/4 float4s
        int i = (blockIdx.y * 192 + blockIdx.x) * 256 + threadIdx.x + threadIdx.y * 32;
        if (i >= MM * CCH / 4) return;
        float4 v = ((const float4*)x)[i];
        union { ushort4 u; f16 h[4]; } o;
        o.h[0] = (f16)v.x; o.h[1] = (f16)v.y; o.h[2] = (f16)v.z; o.h[3] = (f16)v.w;
        ((ushort4*)x16)[i] = o.u;
        return;
    }
    const float* in = (z == 0) ? Wa : Wp;
    f16* out = (z == 0) ? WaT : WpT;
    int Cc = (z == 0) ? N1 : CCH;
    if (blockIdx.x * 32 >= Cc) return;
    __shared__ float tile[32][33];
    int c0 = blockIdx.x * 32, r0 = blockIdx.y * 32;
    int tx = threadIdx.x, ty = threadIdx.y;
#pragma unroll
    for (int k = 0; k < 4; k++) {
        int r = ty + k * 8;
        tile[r][tx] = in[(size_t)(r0 + r) * Cc + c0 + tx];
    }
    __syncthreads();
#pragma unroll
    for (int k = 0; k < 4; k++) {
        int r = ty + k * 8;
        out[(size_t)(c0 + r) * CCH + r0 + tx] = (f16)tile[tx][r];
    }
}

// ------- transpose f16 per-head [T][HD] -> [HD][T] (for V) -------
__global__ void k_trv(const f16* __restrict__ in, f16* __restrict__ out) {
    __shared__ f16 tile[32][34];
    int bh = blockIdx.z;
    int h0 = blockIdx.x * 32, t0 = blockIdx.y * 32;
    int tx = threadIdx.x, ty = threadIdx.y;
#pragma unroll
    for (int k = 0; k < 4; k++) {
        int t = ty + k * 8;
        tile[t][tx] = in[((size_t)bh * TT + t0 + t) * HDIM + h0 + tx];
    }
    __syncthreads();
#pragma unroll
    for (int k = 0; k < 4; k++) {
        int r = ty + k * 8;
        out[((size_t)bh * HDIM + h0 + r) * TT + t0 + tx] = tile[tx][r];
    }
}

// ---------------- global histogram over all B*T tokens ----------------
__global__ void k_hist(const int* __restrict__ tok, int* __restrict__ cnt) {
    int i = blockIdx.x * blockDim.x + threadIdx.x;
    if (i < MM) atomicAdd(cnt + tok[i], 1);
}

// ------- per-batch inclusive scan of 1/count; also padding bias -------
__global__ __launch_bounds__(1024) void k_scan(const int* __restrict__ tok,
                                               const int* __restrict__ cnt,
                                               const int* __restrict__ pm,
                                               float* __restrict__ tpos,
                                               float* __restrict__ pb) {
    __shared__ float s[TT];
    int b = blockIdx.x, t = threadIdx.x;
    s[t] = 1.0f / ((float)cnt[tok[b * TT + t]] + 1e-10f);
    __syncthreads();
    for (int off = 1; off < TT; off <<= 1) {
        float add = (t >= off) ? s[t - off] : 0.0f;
        __syncthreads();
        s[t] += add;
        __syncthreads();
    }
    tpos[b * TT + t] = s[t];
    pb[b * TT + t] = pm[b * TT + t] ? 0.0f : -1e30f;
}

// ------- GEMM: A[M][K] f16, Bt[N][K] f16; 128x128 tile, BK=32 --------
// r5 structure + ONE change: staging pointers hoisted out of the K-loop and
// advanced += 32/iter (attacks the v_lshl_add_u64 address chains = VALUBusy 50%).
// LDS kept as true __shared__ arrays (static addrspace(3)) -- r4's spill
// suspect was generic-pointer LDS aliasing, not hoisting. Tripwire: WRITE_SIZE.
// MODE 0: plain fp32 C write (GEMM2). MODE 1: fused rope/override/v-scale epilogue.
template <int MODE>
__global__ __launch_bounds__(256) void k_gemm(const f16* __restrict__ A,
                                              const f16* __restrict__ Bt,
                                              void* __restrict__ Cp,
                                              const float* __restrict__ tpos,
                                              const float* __restrict__ cs,
                                              f16* __restrict__ qr,
                                              f16* __restrict__ kr,
                                              f16* __restrict__ vsc,
                                              int Mdim, int Ndim, int Kdim) {
    const float SCALE = 0.08838834764831845f;  // 1/sqrt(128), folded into q
    __shared__ __align__(16) f16 As[128 * 32];
    __shared__ __align__(16) f16 Bs[128 * 32];
    int nbn = Ndim >> 7;
    int bm = blockIdx.x / nbn, bn = blockIdx.x % nbn;
    int tid = threadIdx.x;
    int w = tid >> 6, lane = tid & 63, quad = lane >> 4, l16 = lane & 15;
    int rsub = lane >> 2;            // 0..15
    int csub = (lane & 3) << 3;      // 0,8,16,24
    // hoisted staging pointers (advance += 32 elements per k-iter)
    const f16* pa0 = A  + (size_t)((bm << 7) + w * 32 + rsub) * Kdim + csub;
    const f16* pa1 = pa0 + (size_t)16 * Kdim;
    const f16* pb0 = Bt + (size_t)((bn << 7) + w * 32 + rsub) * Kdim + csub;
    const f16* pb1 = pb0 + (size_t)16 * Kdim;
    floatx4 acc[2][8];
#pragma unroll
    for (int i = 0; i < 2; i++)
#pragma unroll
        for (int j = 0; j < 8; j++) acc[i][j] = (floatx4){0.f, 0.f, 0.f, 0.f};
    int nk = Kdim >> 5;
    for (int kt = 0; kt < nk; kt++) {
        __syncthreads();
        g2lds16(pa0, &As[(w * 32) * 32]);
        g2lds16(pa1, &As[(w * 32 + 16) * 32]);
        g2lds16(pb0, &Bs[(w * 32) * 32]);
        g2lds16(pb1, &Bs[(w * 32 + 16) * 32]);
        pa0 += 32; pa1 += 32; pb0 += 32; pb1 += 32;
        __syncthreads();
        half8 af[2], bfr[8];
#pragma unroll
        for (int i = 0; i < 2; i++) af[i] = *(const half8*)&As[(w * 32 + i * 16 + l16) * 32 + (quad << 3)];
#pragma unroll
        for (int j = 0; j < 8; j++) bfr[j] = *(const half8*)&Bs[(j * 16 + l16) * 32 + (quad << 3)];
#pragma unroll
        for (int i = 0; i < 2; i++)
#pragma unroll
            for (int j = 0; j < 8; j++)
                acc[i][j] = __builtin_amdgcn_mfma_f32_16x16x32_f16(af[i], bfr[j], acc[i][j], 0, 0, 0);
    }
    // C rows for this thread: bm*128 + w*32 + i*16 + quad*4 + r ; cols j*16 + l16
    int row0 = (bm << 7) + w * 32 + (quad << 2);
    if (MODE == 0) {
        int cb = (bn << 7) + l16;
#pragma unroll
        for (int i = 0; i < 2; i++)
#pragma unroll
            for (int j = 0; j < 8; j++)
#pragma unroll
                for (int r = 0; r < 4; r++)
                    ((float*)Cp)[(size_t)(row0 + i * 16 + r) * Ndim + cb + j * 16] = acc[i][j][r];
    } else {
        int type = bn >> 4;          // 0=q, 1=k, 2=v (16 col-tiles per 2048-chunk)
        int h = bn & 15;
        if (type < 2) {
            f16* outp = (type == 0) ? qr : kr;
            float invf[4];
#pragma unroll
            for (int jc = 0; jc < 4; jc++)
                invf[jc] = expf((float)(jc * 16 + l16) * -0.14391156929f);  // 10000^(-j/64)
#pragma unroll
            for (int i = 0; i < 2; i++)
#pragma unroll
                for (int r = 0; r < 4; r++) {
                    int row = row0 + i * 16 + r;           // global bt
                    float tp = tpos[row], csv = cs[row];
                    size_t ob = ((size_t)((row >> 10) * HH + h) * TT + (row & 1023)) * HDIM + l16;
#pragma unroll
                    for (int jc = 0; jc < 4; jc++) {
                        float a1 = acc[i][jc][r], a2 = acc[i][jc + 4][r];
                        float sn, cn;
                        sincosf(tp * invf[jc], &sn, &cn);
                        float o1 = a1 * cn - a2 * sn, o2 = a2 * cn + a1 * sn;
                        if (type == 0) {
                            if (jc == 3 && l16 == 15) o2 = 1.0f;      // q[...,-1]=1
                            o1 *= SCALE; o2 *= SCALE;
                        } else {
                            if (jc == 3 && l16 == 15) o2 = csv;       // k[...,-1]=cum_scores
                        }
                        outp[ob + jc * 16]      = (f16)o1;
                        outp[ob + jc * 16 + 64] = (f16)o2;
                    }
                }
        } else {
#pragma unroll
            for (int i = 0; i < 2; i++)
#pragma unroll
                for (int r = 0; r < 4; r++) {
                    int row = row0 + i * 16 + r;
                    float ve = expf(cs[row]);
                    size_t ob = ((size_t)((row >> 10) * HH + h) * TT + (row & 1023)) * HDIM + l16;
#pragma unroll
                    for (int jc = 0; jc < 8; jc++)
                        vsc[ob + jc * 16] = (f16)(acc[i][jc][r] * ve);
                }
        }
    }
}

// ---------------- causal flash attention, S^T formulation ----------------
// Block handles TWO q-tiles (p, NQT-1-p) sequentially -> every block does
// exactly NQT+1 kv-iters (triangular load balance). 4 waves, wave w owns
// q columns w*16+l16 within the 64-q tile.
__global__ __launch_bounds__(256) void k_attn(const f16* __restrict__ qr,
                                              const f16* __restrict__ kr,
                                              const f16* __restrict__ vt,
                                              const float* __restrict__ pb,
                                              f16* __restrict__ y) {
    __shared__ __align__(16) f16 Ks[64 * 136];   // [kv][hd], pad 128->136
    __shared__ __align__(16) f16 Vs[128 * 72];   // [hd][kv], pad 64->72
    __shared__ float pbs[64];
    int p = blockIdx.x & (NQT / 2 - 1);
    int bh = blockIdx.x >> 3;
    int b = bh >> 4, h = bh & 15;
    int tid = threadIdx.x;
    int w = tid >> 6, lane = tid & 63, quad = lane >> 4, l16 = lane & 15;
#pragma unroll
    for (int pass = 0; pass < 2; pass++) {
        int qt = pass ? (NQT - 1 - p) : p;
        int q0 = qt << 6;
        int qg = q0 + w * 16 + l16;                  // this lane's q column
        const f16* Qp = qr + ((size_t)bh * TT + qg) * HDIM;
        half8 qf[4];                                  // B-op: Q[q=l16][hd=kc*32+quad*8+e]
#pragma unroll
        for (int kc = 0; kc < 4; kc++) qf[kc] = *(const half8*)&Qp[kc * 32 + (quad << 3)];
        floatx4 O[8];                                 // O^T[hd][q] C-frags
#pragma unroll
        for (int i = 0; i < 8; i++) O[i] = (floatx4){0.f, 0.f, 0.f, 0.f};
        float mx = -1e30f, ls = 0.f;
        for (int kt = 0; kt <= qt; kt++) {
            __syncthreads();
            const f16* Kb = kr + ((size_t)bh * TT + (kt << 6)) * HDIM;
            const f16* Vb = vt + (size_t)bh * HDIM * TT + (kt << 6);
#pragma unroll
            for (int i = 0; i < 4; i++) {
                int seg = tid + (i << 8);
                int krow = seg >> 4, kcol = (seg & 15) << 3;
                *(uint4*)&Ks[krow * 136 + kcol] = *(const uint4*)&Kb[(size_t)krow * HDIM + kcol];
                int vrow = seg >> 3, vcol = (seg & 7) << 3;
                *(uint4*)&Vs[vrow * 72 + vcol] = *(const uint4*)&Vb[(size_t)vrow * TT + vcol];
            }
            if (tid < 64) pbs[tid] = pb[b * TT + (kt << 6) + tid];
            __syncthreads();
            // S^T = K * Q^T : C-layout S^T[kv=quad*4+i][q=l16]
            floatx4 Sv[4];
#pragma unroll
            for (int mc = 0; mc < 4; mc++) Sv[mc] = (floatx4){0.f, 0.f, 0.f, 0.f};
#pragma unroll
            for (int kc = 0; kc < 4; kc++)
#pragma unroll
                for (int mc = 0; mc < 4; mc++) {
                    half8 kf = *(const half8*)&Ks[(mc * 16 + l16) * 136 + kc * 32 + (quad << 3)];
                    Sv[mc] = __builtin_amdgcn_mfma_f32_16x16x32_f16(kf, qf[kc], Sv[mc], 0, 0, 0);
                }
            // mask + bias + online softmax (per q column = per lane)
            float pv[4][4];
            float mnew = mx;
#pragma unroll
            for (int mc = 0; mc < 4; mc++) {
                float4 pbv = *(const float4*)&pbs[mc * 16 + (quad << 2)];
#pragma unroll
                for (int i = 0; i < 4; i++) {
                    int kv = (kt << 6) + mc * 16 + (quad << 2) + i;
                    float s = (kv <= qg) ? Sv[mc][i] + ((const float*)&pbv)[i] : -1e30f;
                    pv[mc][i] = s;
                    mnew = fmaxf(mnew, s);
                }
            }
            mnew = fmaxf(mnew, __shfl_xor(mnew, 16));
            mnew = fmaxf(mnew, __shfl_xor(mnew, 32));
            float al = __expf(mx - mnew);
            mx = mnew;
            float psum = 0.f;
#pragma unroll
            for (int mc = 0; mc < 4; mc++)
#pragma unroll
                for (int i = 0; i < 4; i++) {
                    float e = __expf(pv[mc][i] - mnew);
                    pv[mc][i] = e;
                    psum += e;
                }
            psum += __shfl_xor(psum, 16);
            psum += __shfl_xor(psum, 32);
            ls = ls * al + psum;
#pragma unroll
            for (int hm = 0; hm < 8; hm++)
#pragma unroll
                for (int i = 0; i < 4; i++) O[hm][i] *= al;
            // P^T as B-operand of 16x16x16 (k=quad*4+i == C rows). A = V^T.
            half4 pf[4];
#pragma unroll
            for (int mc = 0; mc < 4; mc++) {
                pf[mc][0] = (f16)pv[mc][0]; pf[mc][1] = (f16)pv[mc][1];
                pf[mc][2] = (f16)pv[mc][2]; pf[mc][3] = (f16)pv[mc][3];
            }
#pragma unroll
            for (int mc = 0; mc < 4; mc++)
#pragma unroll
                for (int hm = 0; hm < 8; hm++) {
                    half4 vf = *(const half4*)&Vs[(hm * 16 + l16) * 72 + mc * 16 + (quad << 2)];
                    O[hm] = __builtin_amdgcn_mfma_f32_16x16x16f16(vf, pf[mc], O[hm], 0, 0, 0);
                }
        }
        float inv = 1.0f / ls;
#pragma unroll
        for (int hm = 0; hm < 8; hm++) {
            half4 ov;
#pragma unroll
            for (int i = 0; i < 4; i++) ov[i] = (f16)(O[hm][i] * inv);
            *(half4*)&y[((size_t)b * TT + qg) * CCH + h * HDIM + hm * 16 + (quad << 2)] = ov;
        }
        __syncthreads();   // protect LDS before next pass restages
    }
}

extern "C" void kernel_launch(void* const* d_in, const int* in_sizes, int n_in,
                              void* d_out, int out_size, void* d_ws, size_t ws_size,
                              hipStream_t stream) {
    const float* x   = (const float*)d_in[0];
    const float* cs  = (const float*)d_in[1];
    const int*   tok = (const int*)d_in[2];
    const int*   pm  = (const int*)d_in[3];
    const float* Wa  = (const float*)d_in[4];
    const float* Wp  = (const float*)d_in[5];
    float* out = (float*)d_out;
    char* ws = (char*)d_ws;

    f16* x16 = (f16*)(ws + 0);             // 16 MB ; reused as y after GEMM1
    f16* WaT = (f16*)(ws + 16777216);      // 24 MB
    f16* vt  = (f16*)(ws + 41943040);      // 16 MB   [bh][hd][t]
    f16* WpT = (f16*)(ws + 58720256);      //  8 MB
    f16* qr  = (f16*)(ws + 92274688);      // 16 MB
    f16* kr  = (f16*)(ws + 109051904);     // 16 MB
    f16* vsc = (f16*)(ws + 125829120);     // 16 MB
    int*   cnt  = (int*)(ws + 142606336);  // 4 KB
    float* tpos = (float*)(ws + 142610432);// 16 KB
    float* pb   = (float*)(ws + 142626816);// 16 KB
    f16* y   = x16;

    hipMemsetAsync(cnt, 0, NBLK * sizeof(int), stream);
    k_hist<<<MM / 256, 256, 0, stream>>>(tok, cnt);
    k_scan<<<BB, TT, 0, stream>>>(tok, cnt, pm, tpos, pb);
    k_prep<<<dim3(N1 / 32, CCH / 32, 3), dim3(32, 8), 0, stream>>>(Wa, Wp, x, WaT, WpT, x16);
    k_gemm<1><<<(MM / 128) * (N1 / 128), 256, 0, stream>>>(x16, WaT, nullptr, tpos, cs,
                                                           qr, kr, vsc, MM, N1, CCH);
    k_trv<<<dim3(4, 32, BB * HH), dim3(32, 8), 0, stream>>>(vsc, vt);
    k_attn<<<BB * HH * (NQT / 2), 256, 0, stream>>>(qr, kr, vt, pb, y);
    k_gemm<0><<<(MM / 128) * (CCH / 128), 256, 0, stream>>>(y, WpT, out, nullptr, nullptr,
                                                            nullptr, nullptr, nullptr, MM, CCH, CCH);
}